// Round 1
// baseline (71.249 us; speedup 1.0000x reference)
//
#include <hip/hip_runtime.h>
#include <hip/hip_bf16.h>

#define TOK_T 8
#define TOK_H 32
#define TOK_W 32
#define NTOK 8192      // tokens per batch
#define BATCH 2
#define DMODEL 256
#define D3 768
#define NHEADS 8
#define DHEAD 32

using short8 = __attribute__((ext_vector_type(8))) short;
using f32x4  = __attribute__((ext_vector_type(4))) float;

__device__ __forceinline__ ushort f2bf(float f) {
  union { float f; unsigned u; } v; v.f = f;
  unsigned u = v.u;
  unsigned r = (u + 0x7FFFu + ((u >> 16) & 1u)) >> 16;
  return (ushort)r;
}
__device__ __forceinline__ float bf2f(ushort u) {
  union { unsigned u; float f; } v; v.u = ((unsigned)u) << 16;
  return v.f;
}

// ---------------- f32 -> bf16 conversion (vectorized) ----------------
__global__ void f2bf_vec(const float* __restrict__ src, ushort* __restrict__ dst, int n4) {
  int i = blockIdx.x * blockDim.x + threadIdx.x;
  if (i < n4) {
    float4 v = ((const float4*)src)[i];
    ushort4 o;
    o.x = f2bf(v.x); o.y = f2bf(v.y); o.z = f2bf(v.z); o.w = f2bf(v.w);
    ((ushort4*)dst)[i] = o;
  }
}

// ---------------- bf16 GEMM, C = A[M,K] * B[N,K]^T ----------------
// 128x128 tile, BK=32, 4 waves (2x2 of 64x64), mfma_f32_16x16x32_bf16.
// LDS staged via global_load_lds (linear dest); bank-conflict fix via
// slot swizzle k' = k ^ ((r>>1)&3) applied to BOTH global source and ds_read.
#define BM 128
#define BN 128
#define BKK 32

template<bool OUT_BF16>
__global__ __launch_bounds__(256) void gemm_bt(const ushort* __restrict__ A,
                                               const ushort* __restrict__ B,
                                               void* __restrict__ Cv,
                                               int M, int N, int K) {
  __shared__ __align__(16) ushort sA[BM * BKK];
  __shared__ __align__(16) ushort sB[BN * BKK];
  const int tid  = threadIdx.x;
  const int lane = tid & 63;
  const int wid  = tid >> 6;
  const int wr   = wid >> 1;
  const int wc   = wid & 1;
  const int bm   = blockIdx.x * BM;
  const int bn   = blockIdx.y * BN;
  const int fr   = lane & 15;
  const int kb   = lane >> 4;

  f32x4 acc[4][4] = {};

  for (int kt = 0; kt < K; kt += BKK) {
    // stage: 512 chunks of 16B per tile; wave w covers chunks [w*128, w*128+128)
#pragma unroll
    for (int j = 0; j < 2; ++j) {
      int c  = wid * 128 + j * 64 + lane;
      int r  = c >> 2;
      int sl = c & 3;
      int ss = sl ^ ((r >> 1) & 3);   // inverse-swizzled source slot
      const ushort* srcA = A + (size_t)(bm + r) * K + kt + ss * 8;
      const ushort* srcB = B + (size_t)(bn + r) * K + kt + ss * 8;
      ushort* dstA = &sA[(wid * 128 + j * 64) * 8];
      ushort* dstB = &sB[(wid * 128 + j * 64) * 8];
      __builtin_amdgcn_global_load_lds((const __attribute__((address_space(1))) void*)srcA,
                                       (__attribute__((address_space(3))) void*)dstA, 16, 0, 0);
      __builtin_amdgcn_global_load_lds((const __attribute__((address_space(1))) void*)srcB,
                                       (__attribute__((address_space(3))) void*)dstB, 16, 0, 0);
    }
    __syncthreads();

    short8 af[4], bfr[4];
#pragma unroll
    for (int m = 0; m < 4; ++m) {
      int r  = wr * 64 + m * 16 + fr;
      int ck = r * 4 + (kb ^ ((r >> 1) & 3));   // swizzled read
      af[m] = *(const short8*)&sA[ck * 8];
    }
#pragma unroll
    for (int n = 0; n < 4; ++n) {
      int r  = wc * 64 + n * 16 + fr;
      int ck = r * 4 + (kb ^ ((r >> 1) & 3));
      bfr[n] = *(const short8*)&sB[ck * 8];
    }
#pragma unroll
    for (int m = 0; m < 4; ++m)
#pragma unroll
      for (int n = 0; n < 4; ++n)
        acc[m][n] = __builtin_amdgcn_mfma_f32_16x16x32_bf16(af[m], bfr[n], acc[m][n], 0, 0, 0);
    __syncthreads();
  }

  // epilogue: C/D layout col=lane&15, row=(lane>>4)*4+j
  if constexpr (OUT_BF16) {
    ushort* C = (ushort*)Cv;
#pragma unroll
    for (int m = 0; m < 4; ++m)
#pragma unroll
      for (int n = 0; n < 4; ++n)
#pragma unroll
        for (int j = 0; j < 4; ++j) {
          int row = bm + wr * 64 + m * 16 + kb * 4 + j;
          int col = bn + wc * 64 + n * 16 + fr;
          C[(size_t)row * N + col] = f2bf(acc[m][n][j]);
        }
  } else {
    float* C = (float*)Cv;
#pragma unroll
    for (int m = 0; m < 4; ++m)
#pragma unroll
      for (int n = 0; n < 4; ++n)
#pragma unroll
        for (int j = 0; j < 4; ++j) {
          int row = bm + wr * 64 + m * 16 + kb * 4 + j;
          int col = bn + wc * 64 + n * 16 + fr;
          C[(size_t)row * N + col] = acc[m][n][j];
        }
  }
}

// ---------------- local attention ----------------
// One block per (batch, head, 2x8x8 spatial tile); 128 threads = 1 token each.
// Halo 4x10x10 = 400 tokens of k,v (bf16, per-head 32 elems) staged in LDS.
// Zero-padded OOB neighbors give score 0 in softmax, matching the reference.
#define TT 2
#define TLH 8
#define TLW 8
#define NHALO 400
#define KPAD 36

__global__ __launch_bounds__(128) void local_attn(const ushort* __restrict__ qkv,
                                                  ushort* __restrict__ aob) {
  __shared__ __align__(16) ushort sk[NHALO * KPAD];
  __shared__ __align__(16) ushort sv[NHALO * KPAD];
  const int tile = blockIdx.x;   // 0..63
  const int head = blockIdx.y;   // 0..7
  const int b    = blockIdx.z;   // 0..1
  const int tz = tile >> 4;      // T/TT = 4
  const int ty = (tile >> 2) & 3;
  const int tx = tile & 3;
  const int t0 = tz * TT, h0 = ty * TLH, w0 = tx * TLW;
  const int tid = threadIdx.x;

  // stage halo (k and v rows for this head), zeros for out-of-bounds
  for (int idx = tid; idx < NHALO; idx += 128) {
    int ht  = idx / 100;
    int rem = idx - ht * 100;
    int hh  = rem / 10;
    int hw  = rem - hh * 10;
    int gt = t0 - 1 + ht, gh = h0 - 1 + hh, gw = w0 - 1 + hw;
    uint2* kd = (uint2*)&sk[idx * KPAD];
    uint2* vd = (uint2*)&sv[idx * KPAD];
    if (gt >= 0 && gt < TOK_T && gh >= 0 && gh < TOK_H && gw >= 0 && gw < TOK_W) {
      size_t base = ((size_t)b * NTOK + (size_t)gt * 1024 + gh * 32 + gw) * D3;
      const uint2* ks = (const uint2*)(qkv + base + DMODEL + head * DHEAD);
      const uint2* vs = (const uint2*)(qkv + base + 2 * DMODEL + head * DHEAD);
#pragma unroll
      for (int c = 0; c < 8; ++c) { kd[c] = ks[c]; vd[c] = vs[c]; }
    } else {
      uint2 z; z.x = 0u; z.y = 0u;
#pragma unroll
      for (int c = 0; c < 8; ++c) { kd[c] = z; vd[c] = z; }
    }
  }
  __syncthreads();

  const int tt = tid >> 6;
  const int th = (tid >> 3) & 7;
  const int tw = tid & 7;
  const int n  = (t0 + tt) * 1024 + (h0 + th) * 32 + (w0 + tw);

  const ushort* qp = qkv + ((size_t)b * NTOK + n) * D3 + head * DHEAD;
  float q[DHEAD];
  {
    ushort qs[DHEAD];
#pragma unroll
    for (int c = 0; c < 8; ++c) *(uint2*)&qs[c * 4] = *(const uint2*)&qp[c * 4];
#pragma unroll
    for (int d = 0; d < DHEAD; ++d) q[d] = bf2f(qs[d]);
  }

  const float scale = 0.1767766952966369f;  // 1/sqrt(32)
  float s[27];
#pragma unroll
  for (int nb = 0; nb < 27; ++nb) {
    int dt = nb / 9, dh = (nb / 3) % 3, dw = nb % 3;
    int hidx = (tt + dt) * 100 + (th + dh) * 10 + (tw + dw);
    const ushort* kp = &sk[hidx * KPAD];
    ushort ks[DHEAD];
#pragma unroll
    for (int c = 0; c < 8; ++c) *(uint2*)&ks[c * 4] = *(const uint2*)&kp[c * 4];
    float a0 = 0.f, a1 = 0.f, a2 = 0.f, a3 = 0.f;
#pragma unroll
    for (int d = 0; d < DHEAD; d += 4) {
      a0 += q[d + 0] * bf2f(ks[d + 0]);
      a1 += q[d + 1] * bf2f(ks[d + 1]);
      a2 += q[d + 2] * bf2f(ks[d + 2]);
      a3 += q[d + 3] * bf2f(ks[d + 3]);
    }
    s[nb] = (a0 + a1 + a2 + a3) * scale;
  }

  float mx = s[0];
#pragma unroll
  for (int nb = 1; nb < 27; ++nb) mx = fmaxf(mx, s[nb]);

  float o[DHEAD] = {};
  float sum = 0.f;
#pragma unroll
  for (int nb = 0; nb < 27; ++nb) {
    int dt = nb / 9, dh = (nb / 3) % 3, dw = nb % 3;
    int hidx = (tt + dt) * 100 + (th + dh) * 10 + (tw + dw);
    const ushort* vp = &sv[hidx * KPAD];
    ushort vv[DHEAD];
#pragma unroll
    for (int c = 0; c < 8; ++c) *(uint2*)&vv[c * 4] = *(const uint2*)&vp[c * 4];
    float p = __expf(s[nb] - mx);
    sum += p;
#pragma unroll
    for (int d = 0; d < DHEAD; ++d) o[d] += p * bf2f(vv[d]);
  }

  float inv = 1.f / sum;
  ushort os[DHEAD];
#pragma unroll
  for (int d = 0; d < DHEAD; ++d) os[d] = f2bf(o[d] * inv);
  ushort* op = aob + ((size_t)b * NTOK + n) * DMODEL + head * DHEAD;
#pragma unroll
  for (int c = 0; c < 8; ++c) *(uint2*)&op[c * 4] = *(const uint2*)&os[c * 4];
}

// ---------------- launch ----------------
extern "C" void kernel_launch(void* const* d_in, const int* in_sizes, int n_in,
                              void* d_out, int out_size, void* d_ws, size_t ws_size,
                              hipStream_t stream) {
  const float* x     = (const float*)d_in[0];
  const float* w_qkv = (const float*)d_in[1];
  const float* w_out = (const float*)d_in[2];
  float* out = (float*)d_out;

  char* ws = (char*)d_ws;
  size_t off = 0;
  ushort* xb    = (ushort*)(ws + off); off += (size_t)BATCH * NTOK * DMODEL * 2;  // 8 MB
  ushort* wqkvb = (ushort*)(ws + off); off += (size_t)D3 * DMODEL * 2;
  ushort* woutb = (ushort*)(ws + off); off += (size_t)DMODEL * DMODEL * 2;
  ushort* qkvb  = (ushort*)(ws + off); off += (size_t)BATCH * NTOK * D3 * 2;      // 24 MB
  ushort* aob   = (ushort*)(ws + off); off += (size_t)BATCH * NTOK * DMODEL * 2;  // 8 MB

  int nx = BATCH * NTOK * DMODEL / 4;
  f2bf_vec<<<(nx + 255) / 256, 256, 0, stream>>>(x, xb, nx);
  int nw1 = D3 * DMODEL / 4;
  f2bf_vec<<<(nw1 + 255) / 256, 256, 0, stream>>>(w_qkv, wqkvb, nw1);
  int nw2 = DMODEL * DMODEL / 4;
  f2bf_vec<<<(nw2 + 255) / 256, 256, 0, stream>>>(w_out, woutb, nw2);

  dim3 g1(BATCH * NTOK / BM, D3 / BN);   // 128 x 6
  gemm_bt<true><<<g1, 256, 0, stream>>>(xb, wqkvb, (void*)qkvb, BATCH * NTOK, D3, DMODEL);

  dim3 ga(64, NHEADS, BATCH);            // tiles x heads x batch
  local_attn<<<ga, 128, 0, stream>>>(qkvb, aob);

  dim3 g2(BATCH * NTOK / BM, DMODEL / BN);  // 128 x 2
  gemm_bt<false><<<g2, 256, 0, stream>>>(aob, woutb, (void*)out, BATCH * NTOK, DMODEL, DMODEL);
}

// Round 2
// 67.388 us; speedup vs baseline: 1.0573x; 1.0573x over previous
//
#include <hip/hip_runtime.h>
#include <hip/hip_bf16.h>

#define TOK_T 8
#define TOK_H 32
#define TOK_W 32
#define NTOK 8192      // tokens per batch
#define BATCH 2
#define DMODEL 256
#define D3 768
#define NHEADS 8
#define DHEAD 32

using short8  = __attribute__((ext_vector_type(8))) short;
using ushort8 = __attribute__((ext_vector_type(8))) unsigned short;
using f32x4   = __attribute__((ext_vector_type(4))) float;

__device__ __forceinline__ ushort f2bf(float f) {
  union { float f; unsigned u; } v; v.f = f;
  unsigned u = v.u;
  unsigned r = (u + 0x7FFFu + ((u >> 16) & 1u)) >> 16;
  return (ushort)r;
}
__device__ __forceinline__ float bf2f(ushort u) {
  union { unsigned u; float f; } v; v.u = ((unsigned)u) << 16;
  return v.f;
}

// ---------------- fused f32 -> bf16 conversion (one launch for all 3 arrays) ----------------
#define NX4  (BATCH * NTOK * DMODEL / 4)   // 1048576
#define NW14 (D3 * DMODEL / 4)             // 49152
#define NW24 (DMODEL * DMODEL / 4)         // 16384

__global__ __launch_bounds__(256) void convert_all(const float* __restrict__ x,
                                                   const float* __restrict__ wq,
                                                   const float* __restrict__ wo,
                                                   ushort* __restrict__ xb,
                                                   ushort* __restrict__ wqb,
                                                   ushort* __restrict__ wob) {
  int i = blockIdx.x * 256 + threadIdx.x;
  const float* src; ushort* dst; int j;
  if (i < NX4)              { src = x;  dst = xb;  j = i; }
  else if (i < NX4 + NW14)  { src = wq; dst = wqb; j = i - NX4; }
  else if (i < NX4 + NW14 + NW24) { src = wo; dst = wob; j = i - NX4 - NW14; }
  else return;
  float4 v = ((const float4*)src)[j];
  ushort4 o;
  o.x = f2bf(v.x); o.y = f2bf(v.y); o.z = f2bf(v.z); o.w = f2bf(v.w);
  ((ushort4*)dst)[j] = o;
}

// ---------------- bf16 GEMM, C = A[M,K] * B[N,K]^T ----------------
// 128x128 tile, BK=32, 4 waves (2x2 of 64x64), mfma_f32_16x16x32_bf16.
// Double-buffered LDS (2-phase): stage(t+1) issued before compute(t).
// Bank-conflict fix: slot swizzle k' = k ^ ((r>>1)&3) on BOTH global src and ds_read.
#define BM 128
#define BN 128
#define BKK 32

template<bool OUT_BF16>
__global__ __launch_bounds__(256) void gemm_bt(const ushort* __restrict__ A,
                                               const ushort* __restrict__ B,
                                               void* __restrict__ Cv,
                                               int M, int N, int K) {
  __shared__ __align__(16) ushort sA[2][BM * BKK];
  __shared__ __align__(16) ushort sB[2][BN * BKK];
  const int tid  = threadIdx.x;
  const int lane = tid & 63;
  const int wid  = tid >> 6;
  const int wr   = wid >> 1;
  const int wc   = wid & 1;
  const int bm   = blockIdx.x * BM;
  const int bn   = blockIdx.y * BN;
  const int fr   = lane & 15;
  const int kb   = lane >> 4;

  f32x4 acc[4][4] = {};

  auto stage = [&](int buf, int kt) {
#pragma unroll
    for (int j = 0; j < 2; ++j) {
      int c  = wid * 128 + j * 64 + lane;
      int r  = c >> 2;
      int sl = c & 3;
      int ss = sl ^ ((r >> 1) & 3);   // inverse-swizzled source slot
      const ushort* srcA = A + (size_t)(bm + r) * K + kt + ss * 8;
      const ushort* srcB = B + (size_t)(bn + r) * K + kt + ss * 8;
      ushort* dstA = &sA[buf][(wid * 128 + j * 64) * 8];
      ushort* dstB = &sB[buf][(wid * 128 + j * 64) * 8];
      __builtin_amdgcn_global_load_lds((const __attribute__((address_space(1))) void*)srcA,
                                       (__attribute__((address_space(3))) void*)dstA, 16, 0, 0);
      __builtin_amdgcn_global_load_lds((const __attribute__((address_space(1))) void*)srcB,
                                       (__attribute__((address_space(3))) void*)dstB, 16, 0, 0);
    }
  };

  const int nit = K >> 5;
  stage(0, 0);
  __syncthreads();

  for (int it = 0; it < nit; ++it) {
    const int cur = it & 1;
    if (it + 1 < nit) stage(cur ^ 1, (it + 1) << 5);   // prefetch next tile

    short8 af[4], bfr[4];
#pragma unroll
    for (int m = 0; m < 4; ++m) {
      int r  = wr * 64 + m * 16 + fr;
      int ck = r * 4 + (kb ^ ((r >> 1) & 3));   // swizzled read
      af[m] = *(const short8*)&sA[cur][ck * 8];
    }
#pragma unroll
    for (int n = 0; n < 4; ++n) {
      int r  = wc * 64 + n * 16 + fr;
      int ck = r * 4 + (kb ^ ((r >> 1) & 3));
      bfr[n] = *(const short8*)&sB[cur][ck * 8];
    }
#pragma unroll
    for (int m = 0; m < 4; ++m)
#pragma unroll
      for (int n = 0; n < 4; ++n)
        acc[m][n] = __builtin_amdgcn_mfma_f32_16x16x32_bf16(af[m], bfr[n], acc[m][n], 0, 0, 0);
    __syncthreads();   // drains vmcnt(0): next buffer staged and safe
  }

  // epilogue: C/D layout col=lane&15, row=(lane>>4)*4+j
  if constexpr (OUT_BF16) {
    ushort* C = (ushort*)Cv;
#pragma unroll
    for (int m = 0; m < 4; ++m)
#pragma unroll
      for (int n = 0; n < 4; ++n)
#pragma unroll
        for (int j = 0; j < 4; ++j) {
          int row = bm + wr * 64 + m * 16 + kb * 4 + j;
          int col = bn + wc * 64 + n * 16 + fr;
          C[(size_t)row * N + col] = f2bf(acc[m][n][j]);
        }
  } else {
    float* C = (float*)Cv;
#pragma unroll
    for (int m = 0; m < 4; ++m)
#pragma unroll
      for (int n = 0; n < 4; ++n)
#pragma unroll
        for (int j = 0; j < 4; ++j) {
          int row = bm + wr * 64 + m * 16 + kb * 4 + j;
          int col = bn + wc * 64 + n * 16 + fr;
          C[(size_t)row * N + col] = acc[m][n][j];
        }
  }
}

// ---------------- local attention ----------------
// One block per (batch, head, 2x8x8 spatial tile); 128 threads = 1 token each.
// Halo 4x10x10 = 400 tokens. ONE 32KB LDS buffer reused: stage K -> scores ->
// barrier -> stage V -> PV. KPAD=40 ushorts (80B rows): b128 reads land in bank
// group (5*hidx + p) mod 8 -- bijective in tw, balanced over all 64 lanes.
#define TT 2
#define TLH 8
#define TLW 8
#define NHALO 400
#define KP 40

__global__ __launch_bounds__(128) void local_attn(const ushort* __restrict__ qkv,
                                                  ushort* __restrict__ aob) {
  __shared__ __align__(16) ushort sh[NHALO * KP];   // 32000 B, reused for K then V
  const int tile = blockIdx.x;   // 0..63
  const int head = blockIdx.y;   // 0..7
  const int b    = blockIdx.z;   // 0..1
  const int tz = tile >> 4;
  const int ty = (tile >> 2) & 3;
  const int tx = tile & 3;
  const int t0 = tz * TT, h0 = ty * TLH, w0 = tx * TLW;
  const int tid = threadIdx.x;

  auto stage = [&](int ofs) {   // ofs = DMODEL for K, 2*DMODEL for V
    for (int idx = tid; idx < NHALO; idx += 128) {
      int ht  = idx / 100;
      int rem = idx - ht * 100;
      int hh  = rem / 10;
      int hw  = rem - hh * 10;
      int gt = t0 - 1 + ht, gh = h0 - 1 + hh, gw = w0 - 1 + hw;
      ushort8* dst = (ushort8*)&sh[idx * KP];
      if (gt >= 0 && gt < TOK_T && gh >= 0 && gh < TOK_H && gw >= 0 && gw < TOK_W) {
        size_t base = ((size_t)b * NTOK + (size_t)gt * 1024 + gh * 32 + gw) * D3;
        const ushort8* s = (const ushort8*)(qkv + base + ofs + head * DHEAD);
#pragma unroll
        for (int p = 0; p < 4; ++p) dst[p] = s[p];
      } else {
        ushort8 z = (ushort8)0;
#pragma unroll
        for (int p = 0; p < 4; ++p) dst[p] = z;
      }
    }
  };

  // ---- stage K ----
  stage(DMODEL);

  const int tt = tid >> 6;
  const int th = (tid >> 3) & 7;
  const int tw = tid & 7;
  const int n  = (t0 + tt) * 1024 + (h0 + th) * 32 + (w0 + tw);

  // q in registers (global read overlaps K staging latency-wise)
  const ushort* qp = qkv + ((size_t)b * NTOK + n) * D3 + head * DHEAD;
  float q[DHEAD];
  {
    const ushort8* qs = (const ushort8*)qp;
#pragma unroll
    for (int p = 0; p < 4; ++p) {
      ushort8 v = qs[p];
#pragma unroll
      for (int e = 0; e < 8; ++e) q[p * 8 + e] = bf2f(v[e]);
    }
  }
  __syncthreads();

  // ---- scores ----
  const float scale = 0.1767766952966369f;  // 1/sqrt(32)
  float s[27];
#pragma unroll
  for (int nb = 0; nb < 27; ++nb) {
    int dt = nb / 9, dh = (nb / 3) % 3, dw = nb % 3;
    int hidx = (tt + dt) * 100 + (th + dh) * 10 + (tw + dw);
    const ushort8* kp = (const ushort8*)&sh[hidx * KP];
    float a = 0.f;
#pragma unroll
    for (int p = 0; p < 4; ++p) {
      ushort8 kk = kp[p];
#pragma unroll
      for (int e = 0; e < 8; ++e) a += q[p * 8 + e] * bf2f(kk[e]);
    }
    s[nb] = a * scale;
  }
  __syncthreads();   // all K reads done before V overwrites

  // ---- stage V (same buffer) ----
  stage(2 * DMODEL);

  float mx = s[0];
#pragma unroll
  for (int nb = 1; nb < 27; ++nb) mx = fmaxf(mx, s[nb]);
  __syncthreads();

  // ---- softmax + PV ----
  float o[DHEAD] = {};
  float sum = 0.f;
#pragma unroll
  for (int nb = 0; nb < 27; ++nb) {
    int dt = nb / 9, dh = (nb / 3) % 3, dw = nb % 3;
    int hidx = (tt + dt) * 100 + (th + dh) * 10 + (tw + dw);
    const ushort8* vp = (const ushort8*)&sh[hidx * KP];
    float p = __expf(s[nb] - mx);
    sum += p;
#pragma unroll
    for (int c = 0; c < 4; ++c) {
      ushort8 vv = vp[c];
#pragma unroll
      for (int e = 0; e < 8; ++e) o[c * 8 + e] += p * bf2f(vv[e]);
    }
  }

  float inv = 1.f / sum;
  ushort8 os[4];
#pragma unroll
  for (int c = 0; c < 4; ++c)
#pragma unroll
    for (int e = 0; e < 8; ++e) os[c][e] = f2bf(o[c * 8 + e] * inv);
  ushort8* op = (ushort8*)(aob + ((size_t)b * NTOK + n) * DMODEL + head * DHEAD);
#pragma unroll
  for (int c = 0; c < 4; ++c) op[c] = os[c];
}

// ---------------- launch ----------------
extern "C" void kernel_launch(void* const* d_in, const int* in_sizes, int n_in,
                              void* d_out, int out_size, void* d_ws, size_t ws_size,
                              hipStream_t stream) {
  const float* x     = (const float*)d_in[0];
  const float* w_qkv = (const float*)d_in[1];
  const float* w_out = (const float*)d_in[2];
  float* out = (float*)d_out;

  char* ws = (char*)d_ws;
  size_t off = 0;
  ushort* xb    = (ushort*)(ws + off); off += (size_t)BATCH * NTOK * DMODEL * 2;  // 8 MB
  ushort* wqkvb = (ushort*)(ws + off); off += (size_t)D3 * DMODEL * 2;
  ushort* woutb = (ushort*)(ws + off); off += (size_t)DMODEL * DMODEL * 2;
  ushort* qkvb  = (ushort*)(ws + off); off += (size_t)BATCH * NTOK * D3 * 2;      // 24 MB
  ushort* aob   = (ushort*)(ws + off); off += (size_t)BATCH * NTOK * DMODEL * 2;  // 8 MB

  int ntot = NX4 + NW14 + NW24;
  convert_all<<<(ntot + 255) / 256, 256, 0, stream>>>(x, w_qkv, w_out, xb, wqkvb, woutb);

  dim3 g1(BATCH * NTOK / BM, D3 / BN);   // 128 x 6
  gemm_bt<true><<<g1, 256, 0, stream>>>(xb, wqkvb, (void*)qkvb, BATCH * NTOK, D3, DMODEL);

  dim3 ga(64, NHEADS, BATCH);            // tiles x heads x batch
  local_attn<<<ga, 128, 0, stream>>>(qkvb, aob);

  dim3 g2(BATCH * NTOK / BM, DMODEL / BN);  // 128 x 2
  gemm_bt<false><<<g2, 256, 0, stream>>>(aob, woutb, (void*)out, BATCH * NTOK, DMODEL, DMODEL);
}